// Round 2
// baseline (263.031 us; speedup 1.0000x reference)
//
#include <hip/hip_runtime.h>
#include <hip/hip_bf16.h>

#define N_PTS   65432
#define C_DIM   64
#define H_HEADS 4
#define D_HEAD  16
#define K_WIN   256
#define NPAD    65536
#define P_PATCH 256
#define POS_BND 20
#define RPE_NUM 41          // 2*POS_BND+1
#define QKV_DIM 192

// ---------------------------------------------------------------------------
// Kernel 1: gather feat by `order`, pad with zeros, project to qkv [NPAD][192]
// grid = NPAD/64 = 1024 blocks, 256 threads.
// ---------------------------------------------------------------------------
__global__ __launch_bounds__(256) void qkv_kernel(
    const float* __restrict__ feat, const float* __restrict__ qkv_w,
    const float* __restrict__ qkv_b, const int* __restrict__ order,
    float* __restrict__ qkv)
{
    __shared__ float fS[64 * 68];     // padded stride 68 (float4-aligned, no bank aliasing)
    __shared__ float wS[192 * 68];
    __shared__ float bS[192];

    const int t  = threadIdx.x;
    const int bx = blockIdx.x;

    // stage W (192x64), coalesced
    #pragma unroll
    for (int s = 0; s < 48; ++s) {
        int idx = t + 256 * s;
        int row = idx >> 6, col = idx & 63;
        wS[row * 68 + col] = qkv_w[idx];
    }
    if (t < QKV_DIM) bS[t] = qkv_b[t];

    // stage 64 gathered feat rows (zeros for pad rows)
    {
        int rr = t >> 2, part = t & 3;
        int r = bx * 64 + rr;
        int orig = (r < N_PTS) ? order[r] : -1;
        float4 v0, v1, v2, v3;
        if (orig >= 0) {
            const float4* fp = (const float4*)(feat + (size_t)orig * 64 + part * 16);
            v0 = fp[0]; v1 = fp[1]; v2 = fp[2]; v3 = fp[3];
        } else {
            v0 = make_float4(0.f, 0.f, 0.f, 0.f); v1 = v0; v2 = v0; v3 = v0;
        }
        float* dst = fS + rr * 68 + part * 16;
        *(float4*)(dst + 0) = v0; *(float4*)(dst + 4)  = v1;
        *(float4*)(dst + 8) = v2; *(float4*)(dst + 12) = v3;
    }
    __syncthreads();

    // compute: 16 row-groups x 16 col-groups; 4 rows x 12 cols per thread
    const int rg = t >> 4, cg = t & 15;
    float acc[4][12];
    #pragma unroll
    for (int i = 0; i < 4; ++i)
        #pragma unroll
        for (int j = 0; j < 12; ++j) acc[i][j] = 0.f;

    #pragma unroll
    for (int kk = 0; kk < 16; ++kk) {
        float4 f4[4];
        #pragma unroll
        for (int i = 0; i < 4; ++i)
            f4[i] = *(const float4*)&fS[(rg * 4 + i) * 68 + kk * 4];
        #pragma unroll
        for (int j = 0; j < 12; ++j) {
            float4 w4 = *(const float4*)&wS[(cg + 16 * j) * 68 + kk * 4];
            #pragma unroll
            for (int i = 0; i < 4; ++i) {
                acc[i][j] = fmaf(f4[i].x, w4.x, acc[i][j]);
                acc[i][j] = fmaf(f4[i].y, w4.y, acc[i][j]);
                acc[i][j] = fmaf(f4[i].z, w4.z, acc[i][j]);
                acc[i][j] = fmaf(f4[i].w, w4.w, acc[i][j]);
            }
        }
    }
    #pragma unroll
    for (int i = 0; i < 4; ++i) {
        int r = bx * 64 + rg * 4 + i;
        #pragma unroll
        for (int j = 0; j < 12; ++j) {
            int c = cg + 16 * j;
            qkv[(size_t)r * QKV_DIM + c] = acc[i][j] + bS[c];
        }
    }
}

// ---------------------------------------------------------------------------
// Kernel 2: windowed attention, one block per (patch, head).
// 128 threads, 2 query rows per thread (rows t and t+128) so each broadcast
// k_j / v_j LDS read feeds 2 rows of FMAs. Online softmax, exact rescale
// gated on __any(new max).
// NOTE: the reference uses batch[r] (serialized index, NOT gathered by order)
// for the mask, but grid_coord[order[r]] for the RPE. Match that exactly.
// ---------------------------------------------------------------------------
__global__ __launch_bounds__(128) void attn_kernel(
    const float* __restrict__ qkv, const float* __restrict__ rpe_table,
    const int* __restrict__ order, const int* __restrict__ grid_coord,
    const int* __restrict__ batch, float* __restrict__ attn_out)
{
    __shared__ float kS[256 * 16];
    __shared__ float vS[256 * 16];
    __shared__ int4  gS[256];               // (gx, gy, gz, batch_id)
    __shared__ float rpeS[3 * RPE_NUM];

    const int t = threadIdx.x;
    const int p = blockIdx.x, h = blockIdx.y;

    // stage k, v, coords, batch for the 256 window rows
    for (int rr = t; rr < 256; rr += 128) {
        int r = p * 256 + rr;
        const float* row = qkv + (size_t)r * QKV_DIM;
        #pragma unroll
        for (int d4 = 0; d4 < 4; ++d4) {
            *(float4*)&kS[rr * 16 + d4 * 4] = *(const float4*)(row + 64  + h * 16 + d4 * 4);
            *(float4*)&vS[rr * 16 + d4 * 4] = *(const float4*)(row + 128 + h * 16 + d4 * 4);
        }
        if (r < N_PTS) {
            int orig = order[r];
            gS[rr] = make_int4(grid_coord[orig * 3 + 0], grid_coord[orig * 3 + 1],
                               grid_coord[orig * 3 + 2], batch[r]);   // batch NOT gathered!
        } else {
            gS[rr] = make_int4(0, 0, 0, -1);   // sentinel batch never matches a real one
        }
    }
    for (int i = t; i < 3 * RPE_NUM; i += 128) rpeS[i] = rpe_table[i * H_HEADS + h];
    __syncthreads();

    const float scale = 0.25f;   // 16^-0.5
    const int r0 = p * 256 + t, r1 = r0 + 128;
    const bool ok0 = r0 < N_PTS, ok1 = r1 < N_PTS;

    float q0[16], q1[16];
    {
        const float* a = qkv + (size_t)r0 * QKV_DIM + h * 16;
        const float* b = qkv + (size_t)r1 * QKV_DIM + h * 16;
        #pragma unroll
        for (int d4 = 0; d4 < 4; ++d4) {
            float4 qa = *(const float4*)(a + d4 * 4);
            float4 qb = *(const float4*)(b + d4 * 4);
            q0[d4*4+0] = qa.x * scale; q0[d4*4+1] = qa.y * scale;
            q0[d4*4+2] = qa.z * scale; q0[d4*4+3] = qa.w * scale;
            q1[d4*4+0] = qb.x * scale; q1[d4*4+1] = qb.y * scale;
            q1[d4*4+2] = qb.z * scale; q1[d4*4+3] = qb.w * scale;
        }
    }
    const int4 g0 = gS[t], g1 = gS[t + 128];

    float m0 = -1e30f, l0 = 0.f, m1 = -1e30f, l1 = 0.f;
    float acc0[16], acc1[16];
    #pragma unroll
    for (int d = 0; d < 16; ++d) { acc0[d] = 0.f; acc1[d] = 0.f; }

    for (int j = 0; j < 256; ++j) {
        const int4 gj = gS[j];

        // RPE bias + batch mask, per row
        int dx0 = min(max(g0.x - gj.x, -POS_BND), POS_BND);
        int dy0 = min(max(g0.y - gj.y, -POS_BND), POS_BND);
        int dz0 = min(max(g0.z - gj.z, -POS_BND), POS_BND);
        float s0 = rpeS[dx0 + POS_BND] + rpeS[dy0 + POS_BND + RPE_NUM]
                 + rpeS[dz0 + POS_BND + 2 * RPE_NUM];
        s0 += (g0.w == gj.w) ? 0.f : -1000.f;

        int dx1 = min(max(g1.x - gj.x, -POS_BND), POS_BND);
        int dy1 = min(max(g1.y - gj.y, -POS_BND), POS_BND);
        int dz1 = min(max(g1.z - gj.z, -POS_BND), POS_BND);
        float s1 = rpeS[dx1 + POS_BND] + rpeS[dy1 + POS_BND + RPE_NUM]
                 + rpeS[dz1 + POS_BND + 2 * RPE_NUM];
        s1 += (g1.w == gj.w) ? 0.f : -1000.f;

        // dots
        const float4* kp = (const float4*)&kS[j * 16];
        float4 k0 = kp[0], k1v = kp[1], k2 = kp[2], k3 = kp[3];
        s0 = fmaf(q0[0],  k0.x,  s0); s0 = fmaf(q0[1],  k0.y,  s0);
        s0 = fmaf(q0[2],  k0.z,  s0); s0 = fmaf(q0[3],  k0.w,  s0);
        s0 = fmaf(q0[4],  k1v.x, s0); s0 = fmaf(q0[5],  k1v.y, s0);
        s0 = fmaf(q0[6],  k1v.z, s0); s0 = fmaf(q0[7],  k1v.w, s0);
        s0 = fmaf(q0[8],  k2.x,  s0); s0 = fmaf(q0[9],  k2.y,  s0);
        s0 = fmaf(q0[10], k2.z,  s0); s0 = fmaf(q0[11], k2.w,  s0);
        s0 = fmaf(q0[12], k3.x,  s0); s0 = fmaf(q0[13], k3.y,  s0);
        s0 = fmaf(q0[14], k3.z,  s0); s0 = fmaf(q0[15], k3.w,  s0);
        s1 = fmaf(q1[0],  k0.x,  s1); s1 = fmaf(q1[1],  k0.y,  s1);
        s1 = fmaf(q1[2],  k0.z,  s1); s1 = fmaf(q1[3],  k0.w,  s1);
        s1 = fmaf(q1[4],  k1v.x, s1); s1 = fmaf(q1[5],  k1v.y, s1);
        s1 = fmaf(q1[6],  k1v.z, s1); s1 = fmaf(q1[7],  k1v.w, s1);
        s1 = fmaf(q1[8],  k2.x,  s1); s1 = fmaf(q1[9],  k2.y,  s1);
        s1 = fmaf(q1[10], k2.z,  s1); s1 = fmaf(q1[11], k2.w,  s1);
        s1 = fmaf(q1[12], k3.x,  s1); s1 = fmaf(q1[13], k3.y,  s1);
        s1 = fmaf(q1[14], k3.z,  s1); s1 = fmaf(q1[15], k3.w,  s1);

        // online softmax; rescale only when some lane sees a new max (exact)
        bool nd = (s0 > m0) || (s1 > m1);
        if (__any(nd)) {
            float mn0 = fmaxf(m0, s0);
            float c0  = __expf(m0 - mn0);
            l0 *= c0;
            #pragma unroll
            for (int d = 0; d < 16; ++d) acc0[d] *= c0;
            m0 = mn0;
            float mn1 = fmaxf(m1, s1);
            float c1  = __expf(m1 - mn1);
            l1 *= c1;
            #pragma unroll
            for (int d = 0; d < 16; ++d) acc1[d] *= c1;
            m1 = mn1;
        }
        float p0 = __expf(s0 - m0); l0 += p0;
        float p1 = __expf(s1 - m1); l1 += p1;

        const float4* vp = (const float4*)&vS[j * 16];
        float4 va = vp[0], vb = vp[1], vc = vp[2], vd = vp[3];
        acc0[0]  = fmaf(p0, va.x, acc0[0]);  acc0[1]  = fmaf(p0, va.y, acc0[1]);
        acc0[2]  = fmaf(p0, va.z, acc0[2]);  acc0[3]  = fmaf(p0, va.w, acc0[3]);
        acc0[4]  = fmaf(p0, vb.x, acc0[4]);  acc0[5]  = fmaf(p0, vb.y, acc0[5]);
        acc0[6]  = fmaf(p0, vb.z, acc0[6]);  acc0[7]  = fmaf(p0, vb.w, acc0[7]);
        acc0[8]  = fmaf(p0, vc.x, acc0[8]);  acc0[9]  = fmaf(p0, vc.y, acc0[9]);
        acc0[10] = fmaf(p0, vc.z, acc0[10]); acc0[11] = fmaf(p0, vc.w, acc0[11]);
        acc0[12] = fmaf(p0, vd.x, acc0[12]); acc0[13] = fmaf(p0, vd.y, acc0[13]);
        acc0[14] = fmaf(p0, vd.z, acc0[14]); acc0[15] = fmaf(p0, vd.w, acc0[15]);
        acc1[0]  = fmaf(p1, va.x, acc1[0]);  acc1[1]  = fmaf(p1, va.y, acc1[1]);
        acc1[2]  = fmaf(p1, va.z, acc1[2]);  acc1[3]  = fmaf(p1, va.w, acc1[3]);
        acc1[4]  = fmaf(p1, vb.x, acc1[4]);  acc1[5]  = fmaf(p1, vb.y, acc1[5]);
        acc1[6]  = fmaf(p1, vb.z, acc1[6]);  acc1[7]  = fmaf(p1, vb.w, acc1[7]);
        acc1[8]  = fmaf(p1, vc.x, acc1[8]);  acc1[9]  = fmaf(p1, vc.y, acc1[9]);
        acc1[10] = fmaf(p1, vc.z, acc1[10]); acc1[11] = fmaf(p1, vc.w, acc1[11]);
        acc1[12] = fmaf(p1, vd.x, acc1[12]); acc1[13] = fmaf(p1, vd.y, acc1[13]);
        acc1[14] = fmaf(p1, vd.z, acc1[14]); acc1[15] = fmaf(p1, vd.w, acc1[15]);
    }

    if (ok0) {
        float inv = 1.0f / l0;
        float* o = attn_out + (size_t)r0 * C_DIM + h * 16;
        #pragma unroll
        for (int d = 0; d < 16; ++d) o[d] = acc0[d] * inv;
    }
    if (ok1) {
        float inv = 1.0f / l1;
        float* o = attn_out + (size_t)r1 * C_DIM + h * 16;
        #pragma unroll
        for (int d = 0; d < 16; ++d) o[d] = acc1[d] * inv;
    }
}

// ---------------------------------------------------------------------------
// Kernel 3: un-serialize (gather by inverse) + output projection 64x64
// grid = ceil(N/64) blocks, 256 threads.
// ---------------------------------------------------------------------------
__global__ __launch_bounds__(256) void proj_kernel(
    const float* __restrict__ attn_out, const float* __restrict__ proj_w,
    const float* __restrict__ proj_b, const int* __restrict__ inverse,
    float* __restrict__ out)
{
    __shared__ float xS[64 * 68];
    __shared__ float wS[64 * 68];
    __shared__ float bS[64];

    const int t = threadIdx.x, bx = blockIdx.x;

    #pragma unroll
    for (int s = 0; s < 16; ++s) {
        int idx = t + 256 * s;
        int row = idx >> 6, col = idx & 63;
        wS[row * 68 + col] = proj_w[idx];
    }
    if (t < 64) bS[t] = proj_b[t];

    {
        int rr = t >> 2, part = t & 3;
        int n = bx * 64 + rr;
        int src = (n < N_PTS) ? inverse[n] : -1;
        float4 v0, v1, v2, v3;
        if (src >= 0) {
            const float4* fp = (const float4*)(attn_out + (size_t)src * 64 + part * 16);
            v0 = fp[0]; v1 = fp[1]; v2 = fp[2]; v3 = fp[3];
        } else {
            v0 = make_float4(0.f, 0.f, 0.f, 0.f); v1 = v0; v2 = v0; v3 = v0;
        }
        float* dst = xS + rr * 68 + part * 16;
        *(float4*)(dst + 0) = v0; *(float4*)(dst + 4)  = v1;
        *(float4*)(dst + 8) = v2; *(float4*)(dst + 12) = v3;
    }
    __syncthreads();

    const int rg = t >> 4, cg = t & 15;    // 4 rows x 4 cols per thread
    float acc[4][4];
    #pragma unroll
    for (int i = 0; i < 4; ++i)
        #pragma unroll
        for (int j = 0; j < 4; ++j) acc[i][j] = 0.f;

    #pragma unroll
    for (int kk = 0; kk < 16; ++kk) {
        float4 f4[4];
        #pragma unroll
        for (int i = 0; i < 4; ++i)
            f4[i] = *(const float4*)&xS[(rg * 4 + i) * 68 + kk * 4];
        #pragma unroll
        for (int j = 0; j < 4; ++j) {
            float4 w4 = *(const float4*)&wS[(cg + 16 * j) * 68 + kk * 4];
            #pragma unroll
            for (int i = 0; i < 4; ++i) {
                acc[i][j] = fmaf(f4[i].x, w4.x, acc[i][j]);
                acc[i][j] = fmaf(f4[i].y, w4.y, acc[i][j]);
                acc[i][j] = fmaf(f4[i].z, w4.z, acc[i][j]);
                acc[i][j] = fmaf(f4[i].w, w4.w, acc[i][j]);
            }
        }
    }
    #pragma unroll
    for (int i = 0; i < 4; ++i) {
        int n = bx * 64 + rg * 4 + i;
        if (n < N_PTS) {
            #pragma unroll
            for (int j = 0; j < 4; ++j) {
                int c = cg + 16 * j;
                out[(size_t)n * C_DIM + c] = acc[i][j] + bS[c];
            }
        }
    }
}

// ---------------------------------------------------------------------------
extern "C" void kernel_launch(void* const* d_in, const int* in_sizes, int n_in,
                              void* d_out, int out_size, void* d_ws, size_t ws_size,
                              hipStream_t stream)
{
    const float* feat       = (const float*)d_in[0];
    const float* qkv_w      = (const float*)d_in[1];
    const float* qkv_b      = (const float*)d_in[2];
    const float* proj_w     = (const float*)d_in[3];
    const float* proj_b     = (const float*)d_in[4];
    const float* rpe_table  = (const float*)d_in[5];
    const int*   order      = (const int*)d_in[6];
    const int*   inverse    = (const int*)d_in[7];
    const int*   grid_coord = (const int*)d_in[8];
    const int*   batch      = (const int*)d_in[9];
    float*       out        = (float*)d_out;

    float* qkv      = (float*)d_ws;                       // [NPAD][192]
    float* attn_out = qkv + (size_t)NPAD * QKV_DIM;       // [NPAD][64]

    qkv_kernel<<<NPAD / 64, 256, 0, stream>>>(feat, qkv_w, qkv_b, order, qkv);
    attn_kernel<<<dim3(P_PATCH, H_HEADS), 128, 0, stream>>>(
        qkv, rpe_table, order, grid_coord, batch, attn_out);
    proj_kernel<<<(N_PTS + 63) / 64, 256, 0, stream>>>(
        attn_out, proj_w, proj_b, inverse, out);
}

// Round 11
// 223.224 us; speedup vs baseline: 1.1783x; 1.1783x over previous
//
#include <hip/hip_runtime.h>
#include <hip/hip_bf16.h>

#define N_PTS   65432
#define C_DIM   64
#define H_HEADS 4
#define NPAD    65536
#define P_PATCH 256
#define POS_BND 20
#define RPE_NUM 41          // 2*POS_BND+1
#define QKV_DIM 192
#define LOG2E   1.44269504088896f

// NOTE: must be __fp16 (not _Float16): __builtin_amdgcn_cvt_pkrtz returns
// V2h = __fp16 ext_vector(2), and __builtin_amdgcn_fdot2 takes the same.
typedef __fp16 half2_t __attribute__((ext_vector_type(2)));

static __device__ __forceinline__ half2_t mk_h2(float a, float b) {
#if __has_builtin(__builtin_amdgcn_cvt_pkrtz)
    return __builtin_amdgcn_cvt_pkrtz(a, b);
#else
    half2_t r; r[0] = (__fp16)a; r[1] = (__fp16)b; return r;
#endif
}
static __device__ __forceinline__ float fdot2(half2_t a, half2_t b, float c) {
#if __has_builtin(__builtin_amdgcn_fdot2)
    return __builtin_amdgcn_fdot2(a, b, c, false);
#else
    return fmaf((float)a[0], (float)b[0], fmaf((float)a[1], (float)b[1], c));
#endif
}
static __device__ __forceinline__ float exp2_fast(float x) {
#if __has_builtin(__builtin_amdgcn_exp2f)
    return __builtin_amdgcn_exp2f(x);
#else
    return exp2f(x);
#endif
}

union U4 { uint4 u; half2_t h[4]; };

// ---------------------------------------------------------------------------
// Kernel 1: gather feat by `order`, pad with zeros, project to qkv [NPAD][192]
// (unchanged — not yet evidenced as a bottleneck)
// ---------------------------------------------------------------------------
__global__ __launch_bounds__(256) void qkv_kernel(
    const float* __restrict__ feat, const float* __restrict__ qkv_w,
    const float* __restrict__ qkv_b, const int* __restrict__ order,
    float* __restrict__ qkv)
{
    __shared__ float fS[64 * 68];
    __shared__ float wS[QKV_DIM * 68];
    __shared__ float bS[QKV_DIM];

    const int t  = threadIdx.x;
    const int bx = blockIdx.x;

    #pragma unroll
    for (int s = 0; s < 48; ++s) {
        int idx = t + 256 * s;
        int row = idx >> 6, col = idx & 63;
        wS[row * 68 + col] = qkv_w[idx];
    }
    if (t < QKV_DIM) bS[t] = qkv_b[t];

    {
        int rr = t >> 2, part = t & 3;
        int r = bx * 64 + rr;
        int orig = (r < N_PTS) ? order[r] : -1;
        float4 v0, v1, v2, v3;
        if (orig >= 0) {
            const float4* fp = (const float4*)(feat + (size_t)orig * 64 + part * 16);
            v0 = fp[0]; v1 = fp[1]; v2 = fp[2]; v3 = fp[3];
        } else {
            v0 = make_float4(0.f, 0.f, 0.f, 0.f); v1 = v0; v2 = v0; v3 = v0;
        }
        float* dst = fS + rr * 68 + part * 16;
        *(float4*)(dst + 0) = v0; *(float4*)(dst + 4)  = v1;
        *(float4*)(dst + 8) = v2; *(float4*)(dst + 12) = v3;
    }
    __syncthreads();

    const int rg = t >> 4, cg = t & 15;
    float acc[4][12];
    #pragma unroll
    for (int i = 0; i < 4; ++i)
        #pragma unroll
        for (int j = 0; j < 12; ++j) acc[i][j] = 0.f;

    #pragma unroll
    for (int kk = 0; kk < 16; ++kk) {
        float4 f4[4];
        #pragma unroll
        for (int i = 0; i < 4; ++i)
            f4[i] = *(const float4*)&fS[(rg * 4 + i) * 68 + kk * 4];
        #pragma unroll
        for (int j = 0; j < 12; ++j) {
            float4 w4 = *(const float4*)&wS[(cg + 16 * j) * 68 + kk * 4];
            #pragma unroll
            for (int i = 0; i < 4; ++i) {
                acc[i][j] = fmaf(f4[i].x, w4.x, acc[i][j]);
                acc[i][j] = fmaf(f4[i].y, w4.y, acc[i][j]);
                acc[i][j] = fmaf(f4[i].z, w4.z, acc[i][j]);
                acc[i][j] = fmaf(f4[i].w, w4.w, acc[i][j]);
            }
        }
    }
    #pragma unroll
    for (int i = 0; i < 4; ++i) {
        int r = bx * 64 + rg * 4 + i;
        #pragma unroll
        for (int j = 0; j < 12; ++j) {
            int c = cg + 16 * j;
            qkv[(size_t)r * QKV_DIM + c] = acc[i][j] + bS[c];
        }
    }
}

// ---------------------------------------------------------------------------
// Kernel 2: windowed attention. One block per (patch, head), 256 threads,
// 1 query row per thread (4 waves/block -> 50% occupancy ceiling vs 25%).
// f16 v_dot2 for QK^T and PV (V stored j-pair-transposed as half2).
// log2-domain softmax, per-16j-tile unconditional rescale (no divergence).
// 2D LUT for the x+y RPE terms. batch[r] is NOT gathered by order (ref quirk).
// ---------------------------------------------------------------------------
__global__ __launch_bounds__(256, 4) void attn_kernel(
    const float* __restrict__ qkv, const float* __restrict__ rpe_table,
    const int* __restrict__ order, const int* __restrict__ grid_coord,
    const int* __restrict__ batch, float* __restrict__ attn_out)
{
    __shared__ __align__(16) uint  kS[256 * 8];    // K rows as 8 half2 each
    __shared__ __align__(16) uint  vT[128 * 16];   // V j-pair transposed: [jp][d] half2
    __shared__ float lutS[RPE_NUM * RPE_NUM];      // (tx+ty)*log2e for this head
    __shared__ float zS[RPE_NUM];                  // tz*log2e
    __shared__ int4  gS[256];                      // (gx,gy,gz,batch)

    const int t = threadIdx.x;
    const int p = blockIdx.x, h = blockIdx.y;
    const int r = p * 256 + t;

    // ---- stage K row t as packed f16 pairs (broadcast-read later)
    {
        const float* kp = qkv + (size_t)r * QKV_DIM + 64 + h * 16;
        float4 a = *(const float4*)(kp + 0), b = *(const float4*)(kp + 4);
        float4 c = *(const float4*)(kp + 8), d = *(const float4*)(kp + 12);
        U4 A, B;
        A.h[0] = mk_h2(a.x, a.y); A.h[1] = mk_h2(a.z, a.w);
        A.h[2] = mk_h2(b.x, b.y); A.h[3] = mk_h2(b.z, b.w);
        B.h[0] = mk_h2(c.x, c.y); B.h[1] = mk_h2(c.z, c.w);
        B.h[2] = mk_h2(d.x, d.y); B.h[3] = mk_h2(d.z, d.w);
        *(uint4*)&kS[t * 8]     = A.u;
        *(uint4*)&kS[t * 8 + 4] = B.u;
    }
    // ---- stage V as j-pair half2: vT[jp][d] = (v_{2jp}[d], v_{2jp+1}[d])
    {
        int jp = t >> 1, hf = t & 1;
        const float* v0 = qkv + (size_t)(p * 256 + 2 * jp)     * QKV_DIM + 128 + h * 16 + hf * 8;
        const float* v1 = qkv + (size_t)(p * 256 + 2 * jp + 1) * QKV_DIM + 128 + h * 16 + hf * 8;
        float4 a0 = *(const float4*)(v0), b0 = *(const float4*)(v0 + 4);
        float4 a1 = *(const float4*)(v1), b1 = *(const float4*)(v1 + 4);
        U4 A, B;
        A.h[0] = mk_h2(a0.x, a1.x); A.h[1] = mk_h2(a0.y, a1.y);
        A.h[2] = mk_h2(a0.z, a1.z); A.h[3] = mk_h2(a0.w, a1.w);
        B.h[0] = mk_h2(b0.x, b1.x); B.h[1] = mk_h2(b0.y, b1.y);
        B.h[2] = mk_h2(b0.z, b1.z); B.h[3] = mk_h2(b0.w, b1.w);
        *(uint4*)&vT[jp * 16 + hf * 8]     = A.u;
        *(uint4*)&vT[jp * 16 + hf * 8 + 4] = B.u;
    }
    // ---- coords (gathered by order) + batch (NOT gathered — matches ref)
    if (r < N_PTS) {
        int orig = order[r];
        gS[t] = make_int4(grid_coord[orig * 3 + 0], grid_coord[orig * 3 + 1],
                          grid_coord[orig * 3 + 2], batch[r]);
    } else {
        gS[t] = make_int4(0, 0, 0, -1);   // pad sentinel: never equals a real batch id
    }
    // ---- 2D LUT (x+y) and z table, pre-scaled by log2e
    for (int i = t; i < RPE_NUM * RPE_NUM; i += 256) {
        int a = i / RPE_NUM, b = i - a * RPE_NUM;
        lutS[i] = (rpe_table[a * H_HEADS + h] +
                   rpe_table[(RPE_NUM + b) * H_HEADS + h]) * LOG2E;
    }
    if (t < RPE_NUM) zS[t] = rpe_table[(2 * RPE_NUM + t) * H_HEADS + h] * LOG2E;
    __syncthreads();

    // ---- q for this thread's row, pre-scaled by 0.25*log2e, packed f16
    half2_t qh[8];
    {
        const float QS = 0.25f * LOG2E;
        const float* qp = qkv + (size_t)r * QKV_DIM + h * 16;
        float4 a = *(const float4*)(qp + 0), b = *(const float4*)(qp + 4);
        float4 c = *(const float4*)(qp + 8), d = *(const float4*)(qp + 12);
        qh[0] = mk_h2(a.x * QS, a.y * QS); qh[1] = mk_h2(a.z * QS, a.w * QS);
        qh[2] = mk_h2(b.x * QS, b.y * QS); qh[3] = mk_h2(b.z * QS, b.w * QS);
        qh[4] = mk_h2(c.x * QS, c.y * QS); qh[5] = mk_h2(c.z * QS, c.w * QS);
        qh[6] = mk_h2(d.x * QS, d.y * QS); qh[7] = mk_h2(d.z * QS, d.w * QS);
    }
    const int4 gi = gS[t];

    float m = -1e30f, l = 0.f;
    float acc[16];
    #pragma unroll
    for (int d2 = 0; d2 < 16; ++d2) acc[d2] = 0.f;

    for (int tile = 0; tile < 16; ++tile) {
        float s[16];
        float tmax = -1e30f;
        #pragma unroll
        for (int jj = 0; jj < 16; ++jj) {
            const int j = tile * 16 + jj;
            const int4 gj = gS[j];
            int dx = min(max(gi.x - gj.x, -POS_BND), POS_BND) + POS_BND;
            int dy = min(max(gi.y - gj.y, -POS_BND), POS_BND) + POS_BND;
            int dz = min(max(gi.z - gj.z, -POS_BND), POS_BND) + POS_BND;
            float sv = lutS[dx * RPE_NUM + dy] + zS[dz];
            sv += (gi.w == gj.w) ? 0.f : (-1000.f * LOG2E);
            U4 A, B;
            A.u = *(const uint4*)&kS[j * 8];
            B.u = *(const uint4*)&kS[j * 8 + 4];
            sv = fdot2(A.h[0], qh[0], sv); sv = fdot2(A.h[1], qh[1], sv);
            sv = fdot2(A.h[2], qh[2], sv); sv = fdot2(A.h[3], qh[3], sv);
            sv = fdot2(B.h[0], qh[4], sv); sv = fdot2(B.h[1], qh[5], sv);
            sv = fdot2(B.h[2], qh[6], sv); sv = fdot2(B.h[3], qh[7], sv);
            s[jj] = sv;
            tmax = fmaxf(tmax, sv);
        }
        // one exact rescale per tile (flash-attn tile variant, no branch)
        float mn = fmaxf(m, tmax);
        float cr = exp2_fast(m - mn);
        l *= cr;
        #pragma unroll
        for (int d2 = 0; d2 < 16; ++d2) acc[d2] *= cr;
        m = mn;

        half2_t pp[8];
        #pragma unroll
        for (int u = 0; u < 8; ++u) {
            float p0 = exp2_fast(s[2 * u]     - m);
            float p1 = exp2_fast(s[2 * u + 1] - m);
            l += p0 + p1;
            pp[u] = mk_h2(p0, p1);
        }
        #pragma unroll
        for (int u = 0; u < 8; ++u) {
            const int jp = tile * 8 + u;
            U4 A, B, C, D;
            A.u = *(const uint4*)&vT[jp * 16 + 0];
            B.u = *(const uint4*)&vT[jp * 16 + 4];
            C.u = *(const uint4*)&vT[jp * 16 + 8];
            D.u = *(const uint4*)&vT[jp * 16 + 12];
            acc[0]  = fdot2(pp[u], A.h[0], acc[0]);
            acc[1]  = fdot2(pp[u], A.h[1], acc[1]);
            acc[2]  = fdot2(pp[u], A.h[2], acc[2]);
            acc[3]  = fdot2(pp[u], A.h[3], acc[3]);
            acc[4]  = fdot2(pp[u], B.h[0], acc[4]);
            acc[5]  = fdot2(pp[u], B.h[1], acc[5]);
            acc[6]  = fdot2(pp[u], B.h[2], acc[6]);
            acc[7]  = fdot2(pp[u], B.h[3], acc[7]);
            acc[8]  = fdot2(pp[u], C.h[0], acc[8]);
            acc[9]  = fdot2(pp[u], C.h[1], acc[9]);
            acc[10] = fdot2(pp[u], C.h[2], acc[10]);
            acc[11] = fdot2(pp[u], C.h[3], acc[11]);
            acc[12] = fdot2(pp[u], D.h[0], acc[12]);
            acc[13] = fdot2(pp[u], D.h[1], acc[13]);
            acc[14] = fdot2(pp[u], D.h[2], acc[14]);
            acc[15] = fdot2(pp[u], D.h[3], acc[15]);
        }
    }

    if (r < N_PTS) {
        float inv = 1.0f / l;
        float* o = attn_out + (size_t)r * C_DIM + h * 16;
        #pragma unroll
        for (int d2 = 0; d2 < 16; ++d2) o[d2] = acc[d2] * inv;
    }
}

// ---------------------------------------------------------------------------
// Kernel 3: un-serialize (gather by inverse) + output projection 64x64
// (unchanged)
// ---------------------------------------------------------------------------
__global__ __launch_bounds__(256) void proj_kernel(
    const float* __restrict__ attn_out, const float* __restrict__ proj_w,
    const float* __restrict__ proj_b, const int* __restrict__ inverse,
    float* __restrict__ out)
{
    __shared__ float xS[64 * 68];
    __shared__ float wS[64 * 68];
    __shared__ float bS[64];

    const int t = threadIdx.x, bx = blockIdx.x;

    #pragma unroll
    for (int s = 0; s < 16; ++s) {
        int idx = t + 256 * s;
        int row = idx >> 6, col = idx & 63;
        wS[row * 68 + col] = proj_w[idx];
    }
    if (t < 64) bS[t] = proj_b[t];

    {
        int rr = t >> 2, part = t & 3;
        int n = bx * 64 + rr;
        int src = (n < N_PTS) ? inverse[n] : -1;
        float4 v0, v1, v2, v3;
        if (src >= 0) {
            const float4* fp = (const float4*)(attn_out + (size_t)src * 64 + part * 16);
            v0 = fp[0]; v1 = fp[1]; v2 = fp[2]; v3 = fp[3];
        } else {
            v0 = make_float4(0.f, 0.f, 0.f, 0.f); v1 = v0; v2 = v0; v3 = v0;
        }
        float* dst = xS + rr * 68 + part * 16;
        *(float4*)(dst + 0) = v0; *(float4*)(dst + 4)  = v1;
        *(float4*)(dst + 8) = v2; *(float4*)(dst + 12) = v3;
    }
    __syncthreads();

    const int rg = t >> 4, cg = t & 15;
    float acc[4][4];
    #pragma unroll
    for (int i = 0; i < 4; ++i)
        #pragma unroll
        for (int j = 0; j < 4; ++j) acc[i][j] = 0.f;

    #pragma unroll
    for (int kk = 0; kk < 16; ++kk) {
        float4 f4[4];
        #pragma unroll
        for (int i = 0; i < 4; ++i)
            f4[i] = *(const float4*)&xS[(rg * 4 + i) * 68 + kk * 4];
        #pragma unroll
        for (int j = 0; j < 4; ++j) {
            float4 w4 = *(const float4*)&wS[(cg + 16 * j) * 68 + kk * 4];
            #pragma unroll
            for (int i = 0; i < 4; ++i) {
                acc[i][j] = fmaf(f4[i].x, w4.x, acc[i][j]);
                acc[i][j] = fmaf(f4[i].y, w4.y, acc[i][j]);
                acc[i][j] = fmaf(f4[i].z, w4.z, acc[i][j]);
                acc[i][j] = fmaf(f4[i].w, w4.w, acc[i][j]);
            }
        }
    }
    #pragma unroll
    for (int i = 0; i < 4; ++i) {
        int n = bx * 64 + rg * 4 + i;
        if (n < N_PTS) {
            #pragma unroll
            for (int j = 0; j < 4; ++j) {
                int c = cg + 16 * j;
                out[(size_t)n * C_DIM + c] = acc[i][j] + bS[c];
            }
        }
    }
}

// ---------------------------------------------------------------------------
extern "C" void kernel_launch(void* const* d_in, const int* in_sizes, int n_in,
                              void* d_out, int out_size, void* d_ws, size_t ws_size,
                              hipStream_t stream)
{
    const float* feat       = (const float*)d_in[0];
    const float* qkv_w      = (const float*)d_in[1];
    const float* qkv_b      = (const float*)d_in[2];
    const float* proj_w     = (const float*)d_in[3];
    const float* proj_b     = (const float*)d_in[4];
    const float* rpe_table  = (const float*)d_in[5];
    const int*   order      = (const int*)d_in[6];
    const int*   inverse    = (const int*)d_in[7];
    const int*   grid_coord = (const int*)d_in[8];
    const int*   batch      = (const int*)d_in[9];
    float*       out        = (float*)d_out;

    float* qkv      = (float*)d_ws;                       // [NPAD][192]
    float* attn_out = qkv + (size_t)NPAD * QKV_DIM;       // [NPAD][64]

    qkv_kernel<<<NPAD / 64, 256, 0, stream>>>(feat, qkv_w, qkv_b, order, qkv);
    attn_kernel<<<dim3(P_PATCH, H_HEADS), 256, 0, stream>>>(
        qkv, rpe_table, order, grid_coord, batch, attn_out);
    proj_kernel<<<(N_PTS + 63) / 64, 256, 0, stream>>>(
        attn_out, proj_w, proj_b, inverse, out);
}

// Round 14
// 219.961 us; speedup vs baseline: 1.1958x; 1.0148x over previous
//
#include <hip/hip_runtime.h>
#include <hip/hip_bf16.h>

#define N_PTS   65432
#define C_DIM   64
#define H_HEADS 4
#define NPAD    65536
#define P_PATCH 256
#define POS_BND 20
#define RPE_NUM 41          // 2*POS_BND+1
#define QKV_DIM 192
#define LOG2E   1.44269504088896f

// NOTE: must be __fp16 (not _Float16): __builtin_amdgcn_cvt_pkrtz returns
// V2h = __fp16 ext_vector(2), and __builtin_amdgcn_fdot2 takes the same.
typedef __fp16 half2_t __attribute__((ext_vector_type(2)));

static __device__ __forceinline__ half2_t mk_h2(float a, float b) {
#if __has_builtin(__builtin_amdgcn_cvt_pkrtz)
    return __builtin_amdgcn_cvt_pkrtz(a, b);
#else
    half2_t r; r[0] = (__fp16)a; r[1] = (__fp16)b; return r;
#endif
}
static __device__ __forceinline__ float fdot2(half2_t a, half2_t b, float c) {
#if __has_builtin(__builtin_amdgcn_fdot2)
    return __builtin_amdgcn_fdot2(a, b, c, false);
#else
    return fmaf((float)a[0], (float)b[0], fmaf((float)a[1], (float)b[1], c));
#endif
}
static __device__ __forceinline__ float exp2_fast(float x) {
#if __has_builtin(__builtin_amdgcn_exp2f)
    return __builtin_amdgcn_exp2f(x);
#else
    return exp2f(x);
#endif
}

union U4 { uint4 u; half2_t h[4]; };

// ---------------------------------------------------------------------------
// Kernel 1 (under test): gather feat by `order`, project to qkv.
// Split over column halves: grid 2048 = 1024 row-blocks x 2 col-halves.
// LDS 70.4KB -> 43.9KB per block: 2 -> 3 blocks/CU occupancy cap, and
// halves the per-block W staging (48KB -> 24KB from L2).
// ---------------------------------------------------------------------------
__global__ __launch_bounds__(256) void qkv_kernel(
    const float* __restrict__ feat, const float* __restrict__ qkv_w,
    const float* __restrict__ qkv_b, const int* __restrict__ order,
    float* __restrict__ qkv)
{
    __shared__ float fS[64 * 68];
    __shared__ float wS[96 * 68];
    __shared__ float bS[96];

    const int t  = threadIdx.x;
    const int rb = blockIdx.x >> 1;     // row block: 64 serialized rows
    const int ch = blockIdx.x & 1;      // column half: 96 of 192 cols
    const int c0 = ch * 96;

    // stage this half's W rows (96 x 64), coalesced
    #pragma unroll
    for (int s = 0; s < 24; ++s) {
        int idx = t + 256 * s;          // 0..6143
        int row = idx >> 6, col = idx & 63;
        wS[row * 68 + col] = qkv_w[(size_t)(c0 + row) * 64 + col];
    }
    if (t < 96) bS[t] = qkv_b[c0 + t];

    // stage 64 gathered feat rows (zeros for pad rows)
    {
        int rr = t >> 2, part = t & 3;
        int r = rb * 64 + rr;
        int orig = (r < N_PTS) ? order[r] : -1;
        float4 v0, v1, v2, v3;
        if (orig >= 0) {
            const float4* fp = (const float4*)(feat + (size_t)orig * 64 + part * 16);
            v0 = fp[0]; v1 = fp[1]; v2 = fp[2]; v3 = fp[3];
        } else {
            v0 = make_float4(0.f, 0.f, 0.f, 0.f); v1 = v0; v2 = v0; v3 = v0;
        }
        float* dst = fS + rr * 68 + part * 16;
        *(float4*)(dst + 0) = v0; *(float4*)(dst + 4)  = v1;
        *(float4*)(dst + 8) = v2; *(float4*)(dst + 12) = v3;
    }
    __syncthreads();

    // compute: 16 row-groups x 16 col-groups; 4 rows x 6 cols per thread
    const int rg = t >> 4, cg = t & 15;
    float acc[4][6];
    #pragma unroll
    for (int i = 0; i < 4; ++i)
        #pragma unroll
        for (int j = 0; j < 6; ++j) acc[i][j] = 0.f;

    #pragma unroll
    for (int kk = 0; kk < 16; ++kk) {
        float4 f4[4];
        #pragma unroll
        for (int i = 0; i < 4; ++i)
            f4[i] = *(const float4*)&fS[(rg * 4 + i) * 68 + kk * 4];
        #pragma unroll
        for (int j = 0; j < 6; ++j) {
            float4 w4 = *(const float4*)&wS[(cg + 16 * j) * 68 + kk * 4];
            #pragma unroll
            for (int i = 0; i < 4; ++i) {
                acc[i][j] = fmaf(f4[i].x, w4.x, acc[i][j]);
                acc[i][j] = fmaf(f4[i].y, w4.y, acc[i][j]);
                acc[i][j] = fmaf(f4[i].z, w4.z, acc[i][j]);
                acc[i][j] = fmaf(f4[i].w, w4.w, acc[i][j]);
            }
        }
    }
    #pragma unroll
    for (int i = 0; i < 4; ++i) {
        int r = rb * 64 + rg * 4 + i;
        #pragma unroll
        for (int j = 0; j < 6; ++j) {
            int c = cg + 16 * j;
            qkv[(size_t)r * QKV_DIM + c0 + c] = acc[i][j] + bS[c];
        }
    }
}

// ---------------------------------------------------------------------------
// Kernel 2 (UNCHANGED — control): windowed attention.
// Measured R11: 97us, VALUBusy 66%, Occ 31.6%.
// ---------------------------------------------------------------------------
__global__ __launch_bounds__(256, 4) void attn_kernel(
    const float* __restrict__ qkv, const float* __restrict__ rpe_table,
    const int* __restrict__ order, const int* __restrict__ grid_coord,
    const int* __restrict__ batch, float* __restrict__ attn_out)
{
    __shared__ __align__(16) uint  kS[256 * 8];    // K rows as 8 half2 each
    __shared__ __align__(16) uint  vT[128 * 16];   // V j-pair transposed: [jp][d] half2
    __shared__ float lutS[RPE_NUM * RPE_NUM];      // (tx+ty)*log2e for this head
    __shared__ float zS[RPE_NUM];                  // tz*log2e
    __shared__ int4  gS[256];                      // (gx,gy,gz,batch)

    const int t = threadIdx.x;
    const int p = blockIdx.x, h = blockIdx.y;
    const int r = p * 256 + t;

    // ---- stage K row t as packed f16 pairs (broadcast-read later)
    {
        const float* kp = qkv + (size_t)r * QKV_DIM + 64 + h * 16;
        float4 a = *(const float4*)(kp + 0), b = *(const float4*)(kp + 4);
        float4 c = *(const float4*)(kp + 8), d = *(const float4*)(kp + 12);
        U4 A, B;
        A.h[0] = mk_h2(a.x, a.y); A.h[1] = mk_h2(a.z, a.w);
        A.h[2] = mk_h2(b.x, b.y); A.h[3] = mk_h2(b.z, b.w);
        B.h[0] = mk_h2(c.x, c.y); B.h[1] = mk_h2(c.z, c.w);
        B.h[2] = mk_h2(d.x, d.y); B.h[3] = mk_h2(d.z, d.w);
        *(uint4*)&kS[t * 8]     = A.u;
        *(uint4*)&kS[t * 8 + 4] = B.u;
    }
    // ---- stage V as j-pair half2: vT[jp][d] = (v_{2jp}[d], v_{2jp+1}[d])
    {
        int jp = t >> 1, hf = t & 1;
        const float* v0 = qkv + (size_t)(p * 256 + 2 * jp)     * QKV_DIM + 128 + h * 16 + hf * 8;
        const float* v1 = qkv + (size_t)(p * 256 + 2 * jp + 1) * QKV_DIM + 128 + h * 16 + hf * 8;
        float4 a0 = *(const float4*)(v0), b0 = *(const float4*)(v0 + 4);
        float4 a1 = *(const float4*)(v1), b1 = *(const float4*)(v1 + 4);
        U4 A, B;
        A.h[0] = mk_h2(a0.x, a1.x); A.h[1] = mk_h2(a0.y, a1.y);
        A.h[2] = mk_h2(a0.z, a1.z); A.h[3] = mk_h2(a0.w, a1.w);
        B.h[0] = mk_h2(b0.x, b1.x); B.h[1] = mk_h2(b0.y, b1.y);
        B.h[2] = mk_h2(b0.z, b1.z); B.h[3] = mk_h2(b0.w, b1.w);
        *(uint4*)&vT[jp * 16 + hf * 8]     = A.u;
        *(uint4*)&vT[jp * 16 + hf * 8 + 4] = B.u;
    }
    // ---- coords (gathered by order) + batch (NOT gathered — matches ref)
    if (r < N_PTS) {
        int orig = order[r];
        gS[t] = make_int4(grid_coord[orig * 3 + 0], grid_coord[orig * 3 + 1],
                          grid_coord[orig * 3 + 2], batch[r]);
    } else {
        gS[t] = make_int4(0, 0, 0, -1);   // pad sentinel: never equals a real batch id
    }
    // ---- 2D LUT (x+y) and z table, pre-scaled by log2e
    for (int i = t; i < RPE_NUM * RPE_NUM; i += 256) {
        int a = i / RPE_NUM, b = i - a * RPE_NUM;
        lutS[i] = (rpe_table[a * H_HEADS + h] +
                   rpe_table[(RPE_NUM + b) * H_HEADS + h]) * LOG2E;
    }
    if (t < RPE_NUM) zS[t] = rpe_table[(2 * RPE_NUM + t) * H_HEADS + h] * LOG2E;
    __syncthreads();

    // ---- q for this thread's row, pre-scaled by 0.25*log2e, packed f16
    half2_t qh[8];
    {
        const float QS = 0.25f * LOG2E;
        const float* qp = qkv + (size_t)r * QKV_DIM + h * 16;
        float4 a = *(const float4*)(qp + 0), b = *(const float4*)(qp + 4);
        float4 c = *(const float4*)(qp + 8), d = *(const float4*)(qp + 12);
        qh[0] = mk_h2(a.x * QS, a.y * QS); qh[1] = mk_h2(a.z * QS, a.w * QS);
        qh[2] = mk_h2(b.x * QS, b.y * QS); qh[3] = mk_h2(b.z * QS, b.w * QS);
        qh[4] = mk_h2(c.x * QS, c.y * QS); qh[5] = mk_h2(c.z * QS, c.w * QS);
        qh[6] = mk_h2(d.x * QS, d.y * QS); qh[7] = mk_h2(d.z * QS, d.w * QS);
    }
    const int4 gi = gS[t];

    float m = -1e30f, l = 0.f;
    float acc[16];
    #pragma unroll
    for (int d2 = 0; d2 < 16; ++d2) acc[d2] = 0.f;

    for (int tile = 0; tile < 16; ++tile) {
        float s[16];
        float tmax = -1e30f;
        #pragma unroll
        for (int jj = 0; jj < 16; ++jj) {
            const int j = tile * 16 + jj;
            const int4 gj = gS[j];
            int dx = min(max(gi.x - gj.x, -POS_BND), POS_BND) + POS_BND;
            int dy = min(max(gi.y - gj.y, -POS_BND), POS_BND) + POS_BND;
            int dz = min(max(gi.z - gj.z, -POS_BND), POS_BND) + POS_BND;
            float sv = lutS[dx * RPE_NUM + dy] + zS[dz];
            sv += (gi.w == gj.w) ? 0.f : (-1000.f * LOG2E);
            U4 A, B;
            A.u = *(const uint4*)&kS[j * 8];
            B.u = *(const uint4*)&kS[j * 8 + 4];
            sv = fdot2(A.h[0], qh[0], sv); sv = fdot2(A.h[1], qh[1], sv);
            sv = fdot2(A.h[2], qh[2], sv); sv = fdot2(A.h[3], qh[3], sv);
            sv = fdot2(B.h[0], qh[4], sv); sv = fdot2(B.h[1], qh[5], sv);
            sv = fdot2(B.h[2], qh[6], sv); sv = fdot2(B.h[3], qh[7], sv);
            s[jj] = sv;
            tmax = fmaxf(tmax, sv);
        }
        // one exact rescale per tile (flash-attn tile variant, no branch)
        float mn = fmaxf(m, tmax);
        float cr = exp2_fast(m - mn);
        l *= cr;
        #pragma unroll
        for (int d2 = 0; d2 < 16; ++d2) acc[d2] *= cr;
        m = mn;

        half2_t pp[8];
        #pragma unroll
        for (int u = 0; u < 8; ++u) {
            float p0 = exp2_fast(s[2 * u]     - m);
            float p1 = exp2_fast(s[2 * u + 1] - m);
            l += p0 + p1;
            pp[u] = mk_h2(p0, p1);
        }
        #pragma unroll
        for (int u = 0; u < 8; ++u) {
            const int jp = tile * 8 + u;
            U4 A, B, C, D;
            A.u = *(const uint4*)&vT[jp * 16 + 0];
            B.u = *(const uint4*)&vT[jp * 16 + 4];
            C.u = *(const uint4*)&vT[jp * 16 + 8];
            D.u = *(const uint4*)&vT[jp * 16 + 12];
            acc[0]  = fdot2(pp[u], A.h[0], acc[0]);
            acc[1]  = fdot2(pp[u], A.h[1], acc[1]);
            acc[2]  = fdot2(pp[u], A.h[2], acc[2]);
            acc[3]  = fdot2(pp[u], A.h[3], acc[3]);
            acc[4]  = fdot2(pp[u], B.h[0], acc[4]);
            acc[5]  = fdot2(pp[u], B.h[1], acc[5]);
            acc[6]  = fdot2(pp[u], B.h[2], acc[6]);
            acc[7]  = fdot2(pp[u], B.h[3], acc[7]);
            acc[8]  = fdot2(pp[u], C.h[0], acc[8]);
            acc[9]  = fdot2(pp[u], C.h[1], acc[9]);
            acc[10] = fdot2(pp[u], C.h[2], acc[10]);
            acc[11] = fdot2(pp[u], C.h[3], acc[11]);
            acc[12] = fdot2(pp[u], D.h[0], acc[12]);
            acc[13] = fdot2(pp[u], D.h[1], acc[13]);
            acc[14] = fdot2(pp[u], D.h[2], acc[14]);
            acc[15] = fdot2(pp[u], D.h[3], acc[15]);
        }
    }

    if (r < N_PTS) {
        float inv = 1.0f / l;
        float* o = attn_out + (size_t)r * C_DIM + h * 16;
        #pragma unroll
        for (int d2 = 0; d2 < 16; ++d2) o[d2] = acc[d2] * inv;
    }
}

// ---------------------------------------------------------------------------
// Kernel 3 (UNCHANGED — control): un-serialize + output projection 64x64
// ---------------------------------------------------------------------------
__global__ __launch_bounds__(256) void proj_kernel(
    const float* __restrict__ attn_out, const float* __restrict__ proj_w,
    const float* __restrict__ proj_b, const int* __restrict__ inverse,
    float* __restrict__ out)
{
    __shared__ float xS[64 * 68];
    __shared__ float wS[64 * 68];
    __shared__ float bS[64];

    const int t = threadIdx.x, bx = blockIdx.x;

    #pragma unroll
    for (int s = 0; s < 16; ++s) {
        int idx = t + 256 * s;
        int row = idx >> 6, col = idx & 63;
        wS[row * 68 + col] = proj_w[idx];
    }
    if (t < 64) bS[t] = proj_b[t];

    {
        int rr = t >> 2, part = t & 3;
        int n = bx * 64 + rr;
        int src = (n < N_PTS) ? inverse[n] : -1;
        float4 v0, v1, v2, v3;
        if (src >= 0) {
            const float4* fp = (const float4*)(attn_out + (size_t)src * 64 + part * 16);
            v0 = fp[0]; v1 = fp[1]; v2 = fp[2]; v3 = fp[3];
        } else {
            v0 = make_float4(0.f, 0.f, 0.f, 0.f); v1 = v0; v2 = v0; v3 = v0;
        }
        float* dst = xS + rr * 68 + part * 16;
        *(float4*)(dst + 0) = v0; *(float4*)(dst + 4)  = v1;
        *(float4*)(dst + 8) = v2; *(float4*)(dst + 12) = v3;
    }
    __syncthreads();

    const int rg = t >> 4, cg = t & 15;
    float acc[4][4];
    #pragma unroll
    for (int i = 0; i < 4; ++i)
        #pragma unroll
        for (int j = 0; j < 4; ++j) acc[i][j] = 0.f;

    #pragma unroll
    for (int kk = 0; kk < 16; ++kk) {
        float4 f4[4];
        #pragma unroll
        for (int i = 0; i < 4; ++i)
            f4[i] = *(const float4*)&xS[(rg * 4 + i) * 68 + kk * 4];
        #pragma unroll
        for (int j = 0; j < 4; ++j) {
            float4 w4 = *(const float4*)&wS[(cg + 16 * j) * 68 + kk * 4];
            #pragma unroll
            for (int i = 0; i < 4; ++i) {
                acc[i][j] = fmaf(f4[i].x, w4.x, acc[i][j]);
                acc[i][j] = fmaf(f4[i].y, w4.y, acc[i][j]);
                acc[i][j] = fmaf(f4[i].z, w4.z, acc[i][j]);
                acc[i][j] = fmaf(f4[i].w, w4.w, acc[i][j]);
            }
        }
    }
    #pragma unroll
    for (int i = 0; i < 4; ++i) {
        int n = bx * 64 + rg * 4 + i;
        if (n < N_PTS) {
            #pragma unroll
            for (int j = 0; j < 4; ++j) {
                int c = cg + 16 * j;
                out[(size_t)n * C_DIM + c] = acc[i][j] + bS[c];
            }
        }
    }
}

// ---------------------------------------------------------------------------
extern "C" void kernel_launch(void* const* d_in, const int* in_sizes, int n_in,
                              void* d_out, int out_size, void* d_ws, size_t ws_size,
                              hipStream_t stream)
{
    const float* feat       = (const float*)d_in[0];
    const float* qkv_w      = (const float*)d_in[1];
    const float* qkv_b      = (const float*)d_in[2];
    const float* proj_w     = (const float*)d_in[3];
    const float* proj_b     = (const float*)d_in[4];
    const float* rpe_table  = (const float*)d_in[5];
    const int*   order      = (const int*)d_in[6];
    const int*   inverse    = (const int*)d_in[7];
    const int*   grid_coord = (const int*)d_in[8];
    const int*   batch      = (const int*)d_in[9];
    float*       out        = (float*)d_out;

    float* qkv      = (float*)d_ws;                       // [NPAD][192]
    float* attn_out = qkv + (size_t)NPAD * QKV_DIM;       // [NPAD][64]

    qkv_kernel<<<(NPAD / 64) * 2, 256, 0, stream>>>(feat, qkv_w, qkv_b, order, qkv);
    attn_kernel<<<dim3(P_PATCH, H_HEADS), 256, 0, stream>>>(
        qkv, rpe_table, order, grid_coord, batch, attn_out);
    proj_kernel<<<(N_PTS + 63) / 64, 256, 0, stream>>>(
        attn_out, proj_w, proj_b, inverse, out);
}